// Round 1
// baseline (1466.089 us; speedup 1.0000x reference)
//
#include <hip/hip_runtime.h>
#include <hip/hip_bf16.h>

#define NB    15
#define NMC   10000
#define NTR   20000
#define NTE   10000
#define BSZ   1024
#define NCLS  10

// KDE constants: BW=0.3, KDE_NORM = 2*pi*BW*BW
// k = exp(-d2/(2*BW*BW)) = exp2(-d2 * C), C = log2(e)/(2*BW*BW)
#define KDE_NORM 0.5654866776461628f
#define EXPC     8.014972449383130f   /* 1/(0.18) * log2(e) */

// ws float layout:
//  [0]        cnt
//  [1..15]    hist_tr
//  [16..30]   hist_te
//  [32..46]   S1 (sum p_hs*idx*kde_te per bin)
//  [48..62]   S2 (sum p_hs*idx*kde_tr per bin)
//  [64..1087] cw (1024 floats)
#define WS_FLOATS 1088

__device__ __forceinline__ float fast_exp2(float x) {
#if __has_builtin(__builtin_amdgcn_exp2f)
    return __builtin_amdgcn_exp2f(x);
#else
    return exp2f(x);
#endif
}

// ---------------------------------------------------------------- setup ----
__global__ void setup_k(const int* __restrict__ by, const int* __restrict__ bp,
                        const float* __restrict__ trp, const float* __restrict__ tep,
                        float* __restrict__ ws)
{
    int i    = blockIdx.x * blockDim.x + threadIdx.x;
    int lane = threadIdx.x & 63;

    float c = 0.f;
    if (i < BSZ) {
        c = (by[i] == bp[i]) ? 1.f : 0.f;
        ws[64 + i] = c;
    }
    unsigned long long mc = __ballot(c != 0.f);
    if (lane == 0 && mc) atomicAdd(&ws[0], (float)__popcll(mc));

    float p_tr = (i < NTR) ? trp[i] : -1.f;
    float p_te = (i < NTE) ? tep[i] : -1.f;
    const float step = 1.0f / 15.0f;
    for (int b2 = 0; b2 < NB; b2++) {
        float lo = b2 * step;
        float hi = (b2 == NB - 1) ? 1.0f : (b2 + 1) * step;
        unsigned long long m1 = __ballot(p_tr > lo && p_tr <= hi);
        unsigned long long m2 = __ballot(p_te > lo && p_te <= hi);
        if (lane == 0) {
            if (m1) atomicAdd(&ws[1  + b2], (float)__popcll(m1));
            if (m2) atomicAdd(&ws[16 + b2], (float)__popcll(m2));
        }
    }
}

// ------------------------------------------------------------ heavy KDE ----
template <bool WEIGHTED>
__device__ __forceinline__ float kde_sum(const float4* __restrict__ d4,
                                         const float4* __restrict__ w4,
                                         int ngroups, float qx, float qy)
{
    float a0 = 0.f, a1 = 0.f, a2 = 0.f, a3 = 0.f;
    for (int g = 0; g < ngroups; ++g) {
        float4 P = d4[2 * g];
        float4 Q = d4[2 * g + 1];
        float4 wv;
        if (WEIGHTED) wv = w4[g];
        float dx, dy, t, k;
        dx = qx - P.x; dy = qy - P.y; t = fmaf(dy, dy, dx * dx);
        k = fast_exp2(-(t * EXPC));
        a0 = WEIGHTED ? fmaf(wv.x, k, a0) : (a0 + k);
        dx = qx - P.z; dy = qy - P.w; t = fmaf(dy, dy, dx * dx);
        k = fast_exp2(-(t * EXPC));
        a1 = WEIGHTED ? fmaf(wv.y, k, a1) : (a1 + k);
        dx = qx - Q.x; dy = qy - Q.y; t = fmaf(dy, dy, dx * dx);
        k = fast_exp2(-(t * EXPC));
        a2 = WEIGHTED ? fmaf(wv.z, k, a2) : (a2 + k);
        dx = qx - Q.z; dy = qy - Q.w; t = fmaf(dy, dy, dx * dx);
        k = fast_exp2(-(t * EXPC));
        a3 = WEIGHTED ? fmaf(wv.w, k, a3) : (a3 + k);
    }
    return (a0 + a1) + (a2 + a3);
}

__global__ __launch_bounds__(256) void ec_kde(
    const float*  __restrict__ mc,       // (NB, NMC, 2)
    const float4* __restrict__ train4,   // train_x as float4 (2 pts each)
    const float4* __restrict__ test4,
    const float4* __restrict__ batch4,
    const float4* __restrict__ cw4,      // 1024 weights as float4
    const float*  __restrict__ Wm,       // (2, NCLS)
    const float*  __restrict__ bv,       // (NCLS,)
    const float*  __restrict__ scal,     // ws: [0] = cnt
    float* __restrict__ S1, float* __restrict__ S2)
{
    int bin   = blockIdx.y;
    int m     = blockIdx.x * blockDim.x + threadIdx.x;
    bool valid = (m < NMC);
    int mm    = valid ? m : 0;

    float qx = mc[(bin * NMC + mm) * 2 + 0];
    float qy = mc[(bin * NMC + mm) * 2 + 1];

    float s_tr = kde_sum<false>(train4, nullptr, NTR / 4, qx, qy);
    float s_te = kde_sum<false>(test4,  nullptr, NTE / 4, qx, qy);
    float s_w  = kde_sum<true >(batch4, cw4,     BSZ / 4, qx, qy);

    // softmax-max for idx
    float lmax = -1e30f;
    float l[NCLS];
#pragma unroll
    for (int c = 0; c < NCLS; ++c) {
        l[c] = fmaf(qx, Wm[c], fmaf(qy, Wm[NCLS + c], bv[c]));
        lmax = fmaxf(lmax, l[c]);
    }
    float sume = 0.f;
#pragma unroll
    for (int c = 0; c < NCLS; ++c) sume += expf(l[c] - lmax);
    float hat_s = 1.0f / sume;   // = max softmax

    const float step = 1.0f / 15.0f;
    float lo = bin * step;
    float hi = (bin == NB - 1) ? 1.0f : (bin + 1) * step;
    float idx = (hat_s >= lo && hat_s <= hi) ? 1.f : 0.f;

    float cnt    = scal[0];
    float kde_tr = s_tr * (1.0f / (NTR * KDE_NORM));
    float kde_te = s_te * (1.0f / (NTE * KDE_NORM));
    float kw     = s_w / (fmaxf(cnt, 1.0f) * KDE_NORM);
    float p_y    = cnt * (1.0f / BSZ);
    float p_hs   = kw * p_y / (kde_tr + 1e-8f);
    p_hs = fminf(fmaxf(p_hs, 0.f), 1.f);

    float c1 = valid ? p_hs * idx * kde_te : 0.f;
    float c2 = valid ? p_hs * idx * kde_tr : 0.f;

    // wave reduce
    for (int off = 32; off > 0; off >>= 1) {
        c1 += __shfl_down(c1, off);
        c2 += __shfl_down(c2, off);
    }
    __shared__ float r1[4], r2[4];
    int wid  = threadIdx.x >> 6;
    int lane = threadIdx.x & 63;
    if (lane == 0) { r1[wid] = c1; r2[wid] = c2; }
    __syncthreads();
    if (threadIdx.x == 0) {
        float t1 = (r1[0] + r1[1]) + (r1[2] + r1[3]);
        float t2 = (r2[0] + r2[1]) + (r2[2] + r2[3]);
        atomicAdd(&S1[bin], t1);
        atomicAdd(&S2[bin], t2);
    }
}

// ---------------------------------------------------------------- final ----
__global__ void final_k(const float* __restrict__ ws, float* __restrict__ out)
{
    if (threadIdx.x == 0 && blockIdx.x == 0) {
        float ec = 0.f;
        for (int b = 0; b < NB; ++b) {
            float tr_rate = ws[1  + b] * (1.0f / NTR);
            float te_rate = ws[16 + b] * (1.0f / NTE);
            float s1 = ws[32 + b];
            float s2 = ws[48 + b];
            float At = (tr_rate > 0.f) ? 0.f : 0.f; // placeholder avoid warn
            (void)At;
            float a_te = (te_rate > 0.f) ? (1.0f / te_rate) : 0.f;
            float a_tr = (tr_rate > 0.f) ? (1.0f / tr_rate) : 0.f;
            float integral = (a_te * s1 - a_tr * s2) * (1.0f / NMC) * 100.0f;
            if (te_rate > 0.f) ec += te_rate * fabsf(integral);
        }
        out[0] = ec;
    }
}

// --------------------------------------------------------------- launch ----
extern "C" void kernel_launch(void* const* d_in, const int* in_sizes, int n_in,
                              void* d_out, int out_size, void* d_ws, size_t ws_size,
                              hipStream_t stream)
{
    const float* batch_x = (const float*)d_in[0];   // (1024,2)
    const int*   by      = (const int*)  d_in[1];   // (1024,)
    const int*   bp      = (const int*)  d_in[2];   // (1024,)
    const float* trp     = (const float*)d_in[3];   // (20000,)
    const float* tep     = (const float*)d_in[4];   // (10000,)
    const float* train_x = (const float*)d_in[5];   // (20000,2)
    const float* test_x  = (const float*)d_in[6];   // (10000,2)
    const float* Wm      = (const float*)d_in[7];   // (2,10)
    const float* bv      = (const float*)d_in[8];   // (10,)
    const float* mc      = (const float*)d_in[9];   // (15,10000,2)

    float* ws  = (float*)d_ws;
    float* out = (float*)d_out;

    hipMemsetAsync(d_ws, 0, WS_FLOATS * sizeof(float), stream);

    int nthr = 256;
    int nblk = (NTR + nthr - 1) / nthr;   // covers NTR >= NTE >= BSZ
    setup_k<<<nblk, nthr, 0, stream>>>(by, bp, trp, tep, ws);

    dim3 grid((NMC + 255) / 256, NB);
    ec_kde<<<grid, 256, 0, stream>>>(
        mc,
        (const float4*)train_x, (const float4*)test_x, (const float4*)batch_x,
        (const float4*)(ws + 64),
        Wm, bv, ws, ws + 32, ws + 48);

    final_k<<<1, 64, 0, stream>>>(ws, out);
}

// Round 2
// 1246.677 us; speedup vs baseline: 1.1760x; 1.1760x over previous
//
#include <hip/hip_runtime.h>
#include <hip/hip_bf16.h>

#define NB    15
#define NMC   10000
#define NTR   20000
#define NTE   10000
#define BSZ   1024
#define NCLS  10

// KDE constants: BW=0.3, KDE_NORM = 2*pi*BW*BW
// k = exp(-d2/(2*BW*BW)) = exp2(-d2 * C), C = log2(e)/(2*BW*BW)
#define KDE_NORM  0.5654866776461628f
#define EXPC      8.014972449383130f    /* log2(e)/0.18 */
#define TWO_EXPC  16.029944898766260f   /* 2*EXPC */

#define TILE  256
#define SPLIT 4

// ws float layout:
//  [0]        cnt
//  [1..15]    hist_tr
//  [16..30]   hist_te
//  [32..46]   S1 (sum p_hs*idx*kde_te per bin)
//  [48..62]   S2 (sum p_hs*idx*kde_tr per bin)
//  [64..1087] cw (1024 floats)
#define WS_FLOATS 1088

__device__ __forceinline__ float fast_exp2(float x) {
#if __has_builtin(__builtin_amdgcn_exp2f)
    return __builtin_amdgcn_exp2f(x);
#else
    return exp2f(x);
#endif
}

// ---------------------------------------------------------------- setup ----
__global__ void setup_k(const int* __restrict__ by, const int* __restrict__ bp,
                        const float* __restrict__ trp, const float* __restrict__ tep,
                        float* __restrict__ ws)
{
    int i    = blockIdx.x * blockDim.x + threadIdx.x;
    int lane = threadIdx.x & 63;

    float c = 0.f;
    if (i < BSZ) {
        c = (by[i] == bp[i]) ? 1.f : 0.f;
        ws[64 + i] = c;
    }
    unsigned long long mc = __ballot(c != 0.f);
    if (lane == 0 && mc) atomicAdd(&ws[0], (float)__popcll(mc));

    float p_tr = (i < NTR) ? trp[i] : -1.f;
    float p_te = (i < NTE) ? tep[i] : -1.f;
    const float step = 1.0f / 15.0f;
    for (int b2 = 0; b2 < NB; b2++) {
        float lo = b2 * step;
        float hi = (b2 == NB - 1) ? 1.0f : (b2 + 1) * step;
        unsigned long long m1 = __ballot(p_tr > lo && p_tr <= hi);
        unsigned long long m2 = __ballot(p_te > lo && p_te <= hi);
        if (lane == 0) {
            if (m1) atomicAdd(&ws[1  + b2], (float)__popcll(m1));
            if (m2) atomicAdd(&ws[16 + b2], (float)__popcll(m2));
        }
    }
}

// ------------------------------------------------------------ heavy KDE ----
// Each block: 64 MC points (one per lane), 4 waves each handling one quarter
// of the dataset. Data staged per round into LDS as (a,b,c,w) float4 where
// a=2C*px, b=2C*py, c=-C*(px^2+py^2); k = exp2(qx*a + qy*b + c + qe),
// qe = -C*(qx^2+qy^2).
template <int ROUNDS, bool WEIGHTED>
__device__ __forceinline__ float kde_phase(const float2* __restrict__ pts,
                                           int Nq,                 // points per quarter
                                           float4* tile,
                                           const float* __restrict__ w,
                                           int tid, int wid,
                                           float qx, float qy, float qe)
{
    float acc = 0.f;
    for (int r = 0; r < ROUNDS; ++r) {
        __syncthreads();   // previous round's consumers done
        int off = r * TILE + tid;
#pragma unroll
        for (int s = 0; s < SPLIT; ++s) {
            float4 v;
            if (off < Nq) {
                float2 p = pts[s * Nq + off];
                v.x = TWO_EXPC * p.x;
                v.y = TWO_EXPC * p.y;
                v.z = -EXPC * fmaf(p.x, p.x, p.y * p.y);
                v.w = WEIGHTED ? w[s * Nq + off] : 0.f;
            } else {
                v = make_float4(0.f, 0.f, -1e30f, 0.f);  // exp2 -> 0
            }
            tile[s * TILE + tid] = v;
        }
        __syncthreads();
        const float4* t4 = &tile[wid * TILE];
#pragma unroll 8
        for (int j = 0; j < TILE; ++j) {
            float4 v = t4[j];
            float e = fmaf(qx, v.x, fmaf(qy, v.y, v.z)) + qe;
            float k = fast_exp2(e);
            acc = WEIGHTED ? fmaf(v.w, k, acc) : (acc + k);
        }
    }
    return acc;
}

__global__ __launch_bounds__(256) void ec_kde(
    const float2* __restrict__ mc2,      // (NB, NMC) float2
    const float2* __restrict__ train2,
    const float2* __restrict__ test2,
    const float2* __restrict__ batch2,
    const float*  __restrict__ Wm,       // (2, NCLS)
    const float*  __restrict__ bv,       // (NCLS,)
    const float*  __restrict__ ws,       // [0]=cnt, +64 = cw
    float* __restrict__ S1, float* __restrict__ S2)
{
    __shared__ float4 tile[SPLIT * TILE];   // 16 KB
    __shared__ float  red[3][256];          // 3 KB

    int tid  = threadIdx.x;
    int wid  = tid >> 6;
    int lane = tid & 63;
    int bin  = blockIdx.y;
    int m    = blockIdx.x * 64 + lane;
    int mm   = (m < NMC) ? m : (NMC - 1);

    float2 q = mc2[bin * NMC + mm];
    float qx = q.x, qy = q.y;
    float qe = -EXPC * fmaf(qx, qx, qy * qy);

    float s_tr = kde_phase<20, false>(train2, NTR / 4, tile, nullptr, tid, wid, qx, qy, qe);
    float s_te = kde_phase<10, false>(test2,  NTE / 4, tile, nullptr, tid, wid, qx, qy, qe);
    float s_w  = kde_phase<1,  true >(batch2, BSZ / 4, tile, ws + 64, tid, wid, qx, qy, qe);

    red[0][tid] = s_tr;
    red[1][tid] = s_te;
    red[2][tid] = s_w;
    __syncthreads();

    if (tid < 64) {
        float t_tr = ((red[0][tid] + red[0][tid + 64]) + (red[0][tid + 128] + red[0][tid + 192]));
        float t_te = ((red[1][tid] + red[1][tid + 64]) + (red[1][tid + 128] + red[1][tid + 192]));
        float t_w  = ((red[2][tid] + red[2][tid + 64]) + (red[2][tid + 128] + red[2][tid + 192]));

        // softmax-max for idx
        float lmax = -1e30f;
        float l[NCLS];
#pragma unroll
        for (int c = 0; c < NCLS; ++c) {
            l[c] = fmaf(qx, Wm[c], fmaf(qy, Wm[NCLS + c], bv[c]));
            lmax = fmaxf(lmax, l[c]);
        }
        float sume = 0.f;
#pragma unroll
        for (int c = 0; c < NCLS; ++c) sume += expf(l[c] - lmax);
        float hat_s = 1.0f / sume;

        const float step = 1.0f / 15.0f;
        float lo = bin * step;
        float hi = (bin == NB - 1) ? 1.0f : (bin + 1) * step;
        float idx = (hat_s >= lo && hat_s <= hi) ? 1.f : 0.f;

        float cnt    = ws[0];
        float kde_tr = t_tr * (1.0f / (NTR * KDE_NORM));
        float kde_te = t_te * (1.0f / (NTE * KDE_NORM));
        float kw     = t_w / (fmaxf(cnt, 1.0f) * KDE_NORM);
        float p_y    = cnt * (1.0f / BSZ);
        float p_hs   = kw * p_y / (kde_tr + 1e-8f);
        p_hs = fminf(fmaxf(p_hs, 0.f), 1.f);

        bool valid = (m < NMC);
        float c1 = valid ? p_hs * idx * kde_te : 0.f;
        float c2 = valid ? p_hs * idx * kde_tr : 0.f;

        for (int off = 32; off > 0; off >>= 1) {
            c1 += __shfl_down(c1, off);
            c2 += __shfl_down(c2, off);
        }
        if (lane == 0) {
            atomicAdd(&S1[bin], c1);
            atomicAdd(&S2[bin], c2);
        }
    }
}

// ---------------------------------------------------------------- final ----
__global__ void final_k(const float* __restrict__ ws, float* __restrict__ out)
{
    if (threadIdx.x == 0 && blockIdx.x == 0) {
        float ec = 0.f;
        for (int b = 0; b < NB; ++b) {
            float tr_rate = ws[1  + b] * (1.0f / NTR);
            float te_rate = ws[16 + b] * (1.0f / NTE);
            float s1 = ws[32 + b];
            float s2 = ws[48 + b];
            float a_te = (te_rate > 0.f) ? (1.0f / te_rate) : 0.f;
            float a_tr = (tr_rate > 0.f) ? (1.0f / tr_rate) : 0.f;
            float integral = (a_te * s1 - a_tr * s2) * (1.0f / NMC) * 100.0f;
            if (te_rate > 0.f) ec += te_rate * fabsf(integral);
        }
        out[0] = ec;
    }
}

// --------------------------------------------------------------- launch ----
extern "C" void kernel_launch(void* const* d_in, const int* in_sizes, int n_in,
                              void* d_out, int out_size, void* d_ws, size_t ws_size,
                              hipStream_t stream)
{
    const float* batch_x = (const float*)d_in[0];   // (1024,2)
    const int*   by      = (const int*)  d_in[1];   // (1024,)
    const int*   bp      = (const int*)  d_in[2];   // (1024,)
    const float* trp     = (const float*)d_in[3];   // (20000,)
    const float* tep     = (const float*)d_in[4];   // (10000,)
    const float* train_x = (const float*)d_in[5];   // (20000,2)
    const float* test_x  = (const float*)d_in[6];   // (10000,2)
    const float* Wm      = (const float*)d_in[7];   // (2,10)
    const float* bv      = (const float*)d_in[8];   // (10,)
    const float* mc      = (const float*)d_in[9];   // (15,10000,2)

    float* ws  = (float*)d_ws;
    float* out = (float*)d_out;

    hipMemsetAsync(d_ws, 0, WS_FLOATS * sizeof(float), stream);

    int nthr = 256;
    int nblk = (NTR + nthr - 1) / nthr;   // covers NTR >= NTE >= BSZ
    setup_k<<<nblk, nthr, 0, stream>>>(by, bp, trp, tep, ws);

    dim3 grid((NMC + 63) / 64, NB);
    ec_kde<<<grid, 256, 0, stream>>>(
        (const float2*)mc,
        (const float2*)train_x, (const float2*)test_x, (const float2*)batch_x,
        Wm, bv, ws, ws + 32, ws + 48);

    final_k<<<1, 64, 0, stream>>>(ws, out);
}

// Round 4
// 748.058 us; speedup vs baseline: 1.9599x; 1.6666x over previous
//
#include <hip/hip_runtime.h>
#include <hip/hip_bf16.h>

#define NB    15
#define NMC   10000
#define NTR   20000
#define NTE   10000
#define BSZ   1024
#define NCLS  10

// KDE constants: BW=0.3, KDE_NORM = 2*pi*BW*BW
// k = exp(-d2/(2*BW*BW)) = exp2(-d2 * C), C = log2(e)/(2*BW*BW)
#define KDE_NORM  0.5654866776461628f
#define EXPC      8.014972449383130f    /* log2(e)/0.18 */
#define TWO_EXPC  16.029944898766260f   /* 2*EXPC */

#define DS    16     // data slices (blockIdx.z)
#define TILE  256    // data points staged per round
#define MQ    8      // MC points per thread

typedef float v2f __attribute__((ext_vector_type(2)));

// ws float layout:
//  [0]        cnt
//  [1..15]    hist_tr
//  [16..30]   hist_te
//  [32..46]   S1
//  [48..62]   S2
//  [64..1087] cw (1024 floats)
//  [1088 ..]  3 planes of NB*NMC per-MC partial sums (tr, te, w)
#define CW_OFF   64
#define P_OFF    1088
#define PLANE    (NB * NMC)
#define WS_SMALL 1088
#define WS_BIG   (P_OFF + 3 * PLANE)

__device__ __forceinline__ float fast_exp2(float x) {
#if __has_builtin(__builtin_amdgcn_exp2f)
    return __builtin_amdgcn_exp2f(x);
#else
    return exp2f(x);
#endif
}

// ---------------------------------------------------------------- setup ----
__global__ void setup_k(const int* __restrict__ by, const int* __restrict__ bp,
                        const float* __restrict__ trp, const float* __restrict__ tep,
                        float* __restrict__ ws)
{
    int i    = blockIdx.x * blockDim.x + threadIdx.x;
    int lane = threadIdx.x & 63;

    float c = 0.f;
    if (i < BSZ) {
        c = (by[i] == bp[i]) ? 1.f : 0.f;
        ws[CW_OFF + i] = c;
    }
    unsigned long long mc = __ballot(c != 0.f);
    if (lane == 0 && mc) atomicAdd(&ws[0], (float)__popcll(mc));

    float p_tr = (i < NTR) ? trp[i] : -1.f;
    float p_te = (i < NTE) ? tep[i] : -1.f;
    const float step = 1.0f / 15.0f;
    for (int b2 = 0; b2 < NB; b2++) {
        float lo = b2 * step;
        float hi = (b2 == NB - 1) ? 1.0f : (b2 + 1) * step;
        unsigned long long m1 = __ballot(p_tr > lo && p_tr <= hi);
        unsigned long long m2 = __ballot(p_te > lo && p_te <= hi);
        if (lane == 0) {
            if (m1) atomicAdd(&ws[1  + b2], (float)__popcll(m1));
            if (m2) atomicAdd(&ws[16 + b2], (float)__popcll(m2));
        }
    }
}

// ------------------------------------------------------------ heavy KDE ----
// LDS tile: pairs of points stored as (a0,a1,b0,b1) + (c0,c1,w0,w1) so packed
// fp32 ops see register-adjacent operands. e = qx*a + qy*b + c + qe  (qe is
// KEPT inside the exponent — the full kernel value accumulates in P; combine
// must NOT rescale).  Padded slots: a=b=0, c=-1e30 -> k=0.
template <bool W>
__device__ __forceinline__ void phase(const float2* __restrict__ pts,
                                      const float* __restrict__ wgt,
                                      int N, int slice,
                                      float* sAB, float* sCW,
                                      const float* qx, const float* qy, const float* qe,
                                      v2f* acc, int tid)
{
    int L      = (N + DS - 1) / DS;
    int start  = slice * L;
    int len    = min(L, N - start);
    int rounds = (len + TILE - 1) / TILE;
    for (int r = 0; r < rounds; ++r) {
        __syncthreads();
        int o = r * TILE + tid;
        float a = 0.f, b = 0.f, c = -1e30f, wv = 0.f;
        if (o < len) {
            float2 p = pts[start + o];
            a = TWO_EXPC * p.x;
            b = TWO_EXPC * p.y;
            c = -EXPC * fmaf(p.x, p.x, p.y * p.y);
            if (W) wv = wgt[start + o];
        }
        int g4 = 4 * (tid >> 1) + (tid & 1);
        sAB[g4] = a;  sAB[g4 + 2] = b;
        sCW[g4] = c;  sCW[g4 + 2] = wv;
        __syncthreads();

        int cnt = min(TILE, len - r * TILE);
        int ng  = (cnt + 1) >> 1;
        const float4* AB4 = (const float4*)sAB;
        const float4* CW4 = (const float4*)sCW;
#pragma unroll 2
        for (int g = 0; g < ng; ++g) {
            float4 AB = AB4[g];
            float4 CW = CW4[g];
            v2f a01 = {AB.x, AB.y};
            v2f b01 = {AB.z, AB.w};
            v2f c01 = {CW.x, CW.y};
            v2f w01 = {CW.z, CW.w};
#pragma unroll
            for (int k = 0; k < MQ; ++k) {
                v2f e = __builtin_elementwise_fma(b01, v2f{qy[k], qy[k]}, c01);
                e = __builtin_elementwise_fma(a01, v2f{qx[k], qx[k]}, e);
                e = e + v2f{qe[k], qe[k]};
                v2f kk;
                kk.x = fast_exp2(e.x);
                kk.y = fast_exp2(e.y);
                acc[k] = W ? __builtin_elementwise_fma(w01, kk, acc[k])
                           : (acc[k] + kk);
            }
        }
    }
}

__global__ __launch_bounds__(256) void kdeA(
    const float2* __restrict__ mc2,
    const float2* __restrict__ tr2,
    const float2* __restrict__ te2,
    const float2* __restrict__ bx2,
    const float*  __restrict__ ws,
    float* __restrict__ P)
{
    __shared__ float sAB[2 * TILE];
    __shared__ float sCW[2 * TILE];

    int tid   = threadIdx.x;
    int bin   = blockIdx.y;
    int slice = blockIdx.z;
    int base  = blockIdx.x * (256 * MQ);

    int qi[MQ];
    float qx[MQ], qy[MQ], qe[MQ];
#pragma unroll
    for (int k = 0; k < MQ; ++k) {
        qi[k] = base + k * 256 + tid;
        int qs = qi[k] < NMC ? qi[k] : (NMC - 1);
        float2 q = mc2[bin * NMC + qs];
        qx[k] = q.x;
        qy[k] = q.y;
        qe[k] = -EXPC * fmaf(q.x, q.x, q.y * q.y);
    }

    v2f accTr[MQ], accTe[MQ], accW[MQ];
#pragma unroll
    for (int k = 0; k < MQ; ++k) {
        accTr[k] = v2f{0.f, 0.f};
        accTe[k] = v2f{0.f, 0.f};
        accW[k]  = v2f{0.f, 0.f};
    }

    phase<false>(tr2, nullptr,     NTR, slice, sAB, sCW, qx, qy, qe, accTr, tid);
    phase<false>(te2, nullptr,     NTE, slice, sAB, sCW, qx, qy, qe, accTe, tid);
    phase<true >(bx2, ws + CW_OFF, BSZ, slice, sAB, sCW, qx, qy, qe, accW,  tid);

#pragma unroll
    for (int k = 0; k < MQ; ++k) {
        if (qi[k] < NMC) {
            int idx = bin * NMC + qi[k];
            atomicAdd(&P[idx],             accTr[k].x + accTr[k].y);
            atomicAdd(&P[PLANE + idx],     accTe[k].x + accTe[k].y);
            atomicAdd(&P[2 * PLANE + idx], accW[k].x  + accW[k].y);
        }
    }
}

// ------------------------------------------------------------- combine ----
// P already holds the full kernel sums (qe was inside the exponent) — use
// them directly. (R3 bug: multiplied by exp2(qe) a second time here.)
__global__ void combine_k(const float2* __restrict__ mc2,
                          const float*  __restrict__ Wm,
                          const float*  __restrict__ bv,
                          const float*  __restrict__ ws,
                          const float*  __restrict__ P,
                          float* __restrict__ S1, float* __restrict__ S2)
{
    int bin  = blockIdx.y;
    int m    = blockIdx.x * 256 + threadIdx.x;
    int lane = threadIdx.x & 63;

    float c1 = 0.f, c2 = 0.f;
    if (m < NMC) {
        float2 q = mc2[bin * NMC + m];
        int idx  = bin * NMC + m;
        float t_tr = P[idx];
        float t_te = P[PLANE + idx];
        float t_w  = P[2 * PLANE + idx];

        float lmax = -1e30f;
        float l[NCLS];
#pragma unroll
        for (int c = 0; c < NCLS; ++c) {
            l[c] = fmaf(q.x, Wm[c], fmaf(q.y, Wm[NCLS + c], bv[c]));
            lmax = fmaxf(lmax, l[c]);
        }
        float sume = 0.f;
#pragma unroll
        for (int c = 0; c < NCLS; ++c) sume += expf(l[c] - lmax);
        float hat_s = 1.0f / sume;

        const float step = 1.0f / 15.0f;
        float lo = bin * step;
        float hi = (bin == NB - 1) ? 1.0f : (bin + 1) * step;
        float ind = (hat_s >= lo && hat_s <= hi) ? 1.f : 0.f;

        float cnt    = ws[0];
        float kde_tr = t_tr * (1.0f / (NTR * KDE_NORM));
        float kde_te = t_te * (1.0f / (NTE * KDE_NORM));
        float kw     = t_w / (fmaxf(cnt, 1.0f) * KDE_NORM);
        float p_y    = cnt * (1.0f / BSZ);
        float p_hs   = kw * p_y / (kde_tr + 1e-8f);
        p_hs = fminf(fmaxf(p_hs, 0.f), 1.f);

        c1 = p_hs * ind * kde_te;
        c2 = p_hs * ind * kde_tr;
    }

    for (int off = 32; off > 0; off >>= 1) {
        c1 += __shfl_down(c1, off);
        c2 += __shfl_down(c2, off);
    }
    if (lane == 0) {
        atomicAdd(&S1[bin], c1);
        atomicAdd(&S2[bin], c2);
    }
}

// ------------------------------------- fallback (small ws): R2 kernel ----
template <int ROUNDS, bool WEIGHTED>
__device__ __forceinline__ float kde_phase_fb(const float2* __restrict__ pts,
                                              int Nq, float4* tile,
                                              const float* __restrict__ w,
                                              int tid, int wid,
                                              float qx, float qy, float qe)
{
    float acc = 0.f;
    for (int r = 0; r < ROUNDS; ++r) {
        __syncthreads();
        int off = r * TILE + tid;
#pragma unroll
        for (int s = 0; s < 4; ++s) {
            float4 v;
            if (off < Nq) {
                float2 p = pts[s * Nq + off];
                v.x = TWO_EXPC * p.x;
                v.y = TWO_EXPC * p.y;
                v.z = -EXPC * fmaf(p.x, p.x, p.y * p.y);
                v.w = WEIGHTED ? w[s * Nq + off] : 0.f;
            } else {
                v = make_float4(0.f, 0.f, -1e30f, 0.f);
            }
            tile[s * TILE + tid] = v;
        }
        __syncthreads();
        const float4* t4 = &tile[wid * TILE];
#pragma unroll 8
        for (int j = 0; j < TILE; ++j) {
            float4 v = t4[j];
            float e = fmaf(qx, v.x, fmaf(qy, v.y, v.z)) + qe;
            float k = fast_exp2(e);
            acc = WEIGHTED ? fmaf(v.w, k, acc) : (acc + k);
        }
    }
    return acc;
}

__global__ __launch_bounds__(256) void ec_kde_fb(
    const float2* __restrict__ mc2, const float2* __restrict__ train2,
    const float2* __restrict__ test2, const float2* __restrict__ batch2,
    const float* __restrict__ Wm, const float* __restrict__ bv,
    const float* __restrict__ ws, float* __restrict__ S1, float* __restrict__ S2)
{
    __shared__ float4 tile[4 * TILE];
    __shared__ float  red[3][256];

    int tid  = threadIdx.x;
    int wid  = tid >> 6;
    int lane = tid & 63;
    int bin  = blockIdx.y;
    int m    = blockIdx.x * 64 + lane;
    int mm   = (m < NMC) ? m : (NMC - 1);

    float2 q = mc2[bin * NMC + mm];
    float qx = q.x, qy = q.y;
    float qe = -EXPC * fmaf(qx, qx, qy * qy);

    float s_tr = kde_phase_fb<20, false>(train2, NTR / 4, tile, nullptr, tid, wid, qx, qy, qe);
    float s_te = kde_phase_fb<10, false>(test2,  NTE / 4, tile, nullptr, tid, wid, qx, qy, qe);
    float s_w  = kde_phase_fb<1,  true >(batch2, BSZ / 4, tile, ws + CW_OFF, tid, wid, qx, qy, qe);

    red[0][tid] = s_tr; red[1][tid] = s_te; red[2][tid] = s_w;
    __syncthreads();

    if (tid < 64) {
        float t_tr = ((red[0][tid] + red[0][tid + 64]) + (red[0][tid + 128] + red[0][tid + 192]));
        float t_te = ((red[1][tid] + red[1][tid + 64]) + (red[1][tid + 128] + red[1][tid + 192]));
        float t_w  = ((red[2][tid] + red[2][tid + 64]) + (red[2][tid + 128] + red[2][tid + 192]));

        float lmax = -1e30f;
        float l[NCLS];
#pragma unroll
        for (int c = 0; c < NCLS; ++c) {
            l[c] = fmaf(qx, Wm[c], fmaf(qy, Wm[NCLS + c], bv[c]));
            lmax = fmaxf(lmax, l[c]);
        }
        float sume = 0.f;
#pragma unroll
        for (int c = 0; c < NCLS; ++c) sume += expf(l[c] - lmax);
        float hat_s = 1.0f / sume;

        const float step = 1.0f / 15.0f;
        float lo = bin * step;
        float hi = (bin == NB - 1) ? 1.0f : (bin + 1) * step;
        float ind = (hat_s >= lo && hat_s <= hi) ? 1.f : 0.f;

        float cnt    = ws[0];
        float kde_tr = t_tr * (1.0f / (NTR * KDE_NORM));
        float kde_te = t_te * (1.0f / (NTE * KDE_NORM));
        float kw     = t_w / (fmaxf(cnt, 1.0f) * KDE_NORM);
        float p_y    = cnt * (1.0f / BSZ);
        float p_hs   = kw * p_y / (kde_tr + 1e-8f);
        p_hs = fminf(fmaxf(p_hs, 0.f), 1.f);

        bool valid = (m < NMC);
        float c1 = valid ? p_hs * ind * kde_te : 0.f;
        float c2 = valid ? p_hs * ind * kde_tr : 0.f;

        for (int off = 32; off > 0; off >>= 1) {
            c1 += __shfl_down(c1, off);
            c2 += __shfl_down(c2, off);
        }
        if (lane == 0) {
            atomicAdd(&S1[bin], c1);
            atomicAdd(&S2[bin], c2);
        }
    }
}

// ---------------------------------------------------------------- final ----
__global__ void final_k(const float* __restrict__ ws, float* __restrict__ out)
{
    if (threadIdx.x == 0 && blockIdx.x == 0) {
        float ec = 0.f;
        for (int b = 0; b < NB; ++b) {
            float tr_rate = ws[1  + b] * (1.0f / NTR);
            float te_rate = ws[16 + b] * (1.0f / NTE);
            float s1 = ws[32 + b];
            float s2 = ws[48 + b];
            float a_te = (te_rate > 0.f) ? (1.0f / te_rate) : 0.f;
            float a_tr = (tr_rate > 0.f) ? (1.0f / tr_rate) : 0.f;
            float integral = (a_te * s1 - a_tr * s2) * (1.0f / NMC) * 100.0f;
            if (te_rate > 0.f) ec += te_rate * fabsf(integral);
        }
        out[0] = ec;
    }
}

// --------------------------------------------------------------- launch ----
extern "C" void kernel_launch(void* const* d_in, const int* in_sizes, int n_in,
                              void* d_out, int out_size, void* d_ws, size_t ws_size,
                              hipStream_t stream)
{
    const float* batch_x = (const float*)d_in[0];
    const int*   by      = (const int*)  d_in[1];
    const int*   bp      = (const int*)  d_in[2];
    const float* trp     = (const float*)d_in[3];
    const float* tep     = (const float*)d_in[4];
    const float* train_x = (const float*)d_in[5];
    const float* test_x  = (const float*)d_in[6];
    const float* Wm      = (const float*)d_in[7];
    const float* bv      = (const float*)d_in[8];
    const float* mc      = (const float*)d_in[9];

    float* ws  = (float*)d_ws;
    float* out = (float*)d_out;

    bool big = ws_size >= (size_t)WS_BIG * sizeof(float);
    size_t zbytes = (big ? WS_BIG : WS_SMALL) * sizeof(float);
    hipMemsetAsync(d_ws, 0, zbytes, stream);

    int nthr = 256;
    int nblk = (NTR + nthr - 1) / nthr;
    setup_k<<<nblk, nthr, 0, stream>>>(by, bp, trp, tep, ws);

    if (big) {
        dim3 gA((NMC + 256 * MQ - 1) / (256 * MQ), NB, DS);
        kdeA<<<gA, 256, 0, stream>>>(
            (const float2*)mc, (const float2*)train_x, (const float2*)test_x,
            (const float2*)batch_x, ws, ws + P_OFF);

        dim3 gB((NMC + 255) / 256, NB);
        combine_k<<<gB, 256, 0, stream>>>(
            (const float2*)mc, Wm, bv, ws, ws + P_OFF, ws + 32, ws + 48);
    } else {
        dim3 grid((NMC + 63) / 64, NB);
        ec_kde_fb<<<grid, 256, 0, stream>>>(
            (const float2*)mc,
            (const float2*)train_x, (const float2*)test_x, (const float2*)batch_x,
            Wm, bv, ws, ws + 32, ws + 48);
    }

    final_k<<<1, 64, 0, stream>>>(ws, out);
}

// Round 5
// 737.347 us; speedup vs baseline: 1.9883x; 1.0145x over previous
//
#include <hip/hip_runtime.h>
#include <hip/hip_bf16.h>

#define NB    15
#define NMC   10000
#define NTR   20000
#define NTE   10000
#define BSZ   1024
#define NCLS  10

// KDE constants: BW=0.3, KDE_NORM = 2*pi*BW*BW
// k = exp(-d2/(2*BW*BW)) = exp2(-d2 * C), C = log2(e)/(2*BW*BW)
#define KDE_NORM  0.5654866776461628f
#define EXPC      8.014972449383130f    /* log2(e)/0.18 */
#define TWO_EXPC  16.029944898766260f   /* 2*EXPC */

#define DS    17     // data slices (blockIdx.z): 5*15*17=1275 blocks ~ 4.98/CU
#define TILE  256    // data points staged per round
#define MQ    8      // MC points per thread

typedef float v2f __attribute__((ext_vector_type(2)));

// ws float layout:
//  [0]        cnt
//  [1..15]    hist_tr
//  [16..30]   hist_te
//  [32..46]   S1
//  [48..62]   S2
//  [64..1087] cw (1024 floats)
//  [1088 ..]  3 planes of NB*NMC per-MC partial sums (tr, te, w)
#define CW_OFF   64
#define P_OFF    1088
#define PLANE    (NB * NMC)
#define WS_SMALL 1088
#define WS_BIG   (P_OFF + 3 * PLANE)

__device__ __forceinline__ float fast_exp2(float x) {
#if __has_builtin(__builtin_amdgcn_exp2f)
    return __builtin_amdgcn_exp2f(x);
#else
    return exp2f(x);
#endif
}

// ---------------------------------------------------------------- setup ----
__global__ void setup_k(const int* __restrict__ by, const int* __restrict__ bp,
                        const float* __restrict__ trp, const float* __restrict__ tep,
                        float* __restrict__ ws)
{
    int i    = blockIdx.x * blockDim.x + threadIdx.x;
    int lane = threadIdx.x & 63;

    float c = 0.f;
    if (i < BSZ) {
        c = (by[i] == bp[i]) ? 1.f : 0.f;
        ws[CW_OFF + i] = c;
    }
    unsigned long long mc = __ballot(c != 0.f);
    if (lane == 0 && mc) atomicAdd(&ws[0], (float)__popcll(mc));

    float p_tr = (i < NTR) ? trp[i] : -1.f;
    float p_te = (i < NTE) ? tep[i] : -1.f;
    const float step = 1.0f / 15.0f;
    for (int b2 = 0; b2 < NB; b2++) {
        float lo = b2 * step;
        float hi = (b2 == NB - 1) ? 1.0f : (b2 + 1) * step;
        unsigned long long m1 = __ballot(p_tr > lo && p_tr <= hi);
        unsigned long long m2 = __ballot(p_te > lo && p_te <= hi);
        if (lane == 0) {
            if (m1) atomicAdd(&ws[1  + b2], (float)__popcll(m1));
            if (m2) atomicAdd(&ws[16 + b2], (float)__popcll(m2));
        }
    }
}

// ------------------------------------------------------------ heavy KDE ----
// LDS tile: pairs of points stored as (a0,a1,b0,b1) + (c0,c1,w0,w1).
// e = qx*a + qy*b + (c + qe)  computed with guaranteed packed fp32 via
// inline asm (R4 post-mortem: compiler scalarized v2f and re-materialized
// broadcasts per body -> ~20 insts/body instead of ~6).
// Padded slots: a=b=0, c=-1e30 -> exp2 -> 0.
template <bool W>
__device__ __forceinline__ void phase(const float2* __restrict__ pts,
                                      const float* __restrict__ wgt,
                                      int N, int slice,
                                      float* sAB, float* sCW,
                                      const float* qx, const float* qy, const float* qe,
                                      v2f* acc, int tid)
{
    // hoisted per-phase broadcast registers (loop-invariant, lives in VGPR pairs)
    v2f qx2[MQ], qy2[MQ], qe2[MQ];
#pragma unroll
    for (int k = 0; k < MQ; ++k) {
        qx2[k] = v2f{qx[k], qx[k]};
        qy2[k] = v2f{qy[k], qy[k]};
        qe2[k] = v2f{qe[k], qe[k]};
        acc[k] = v2f{0.f, 0.f};
    }

    int L      = (N + DS - 1) / DS;
    int start  = slice * L;
    int len    = min(L, N - start);
    int rounds = (len + TILE - 1) / TILE;
    for (int r = 0; r < rounds; ++r) {
        __syncthreads();
        int o = r * TILE + tid;
        float a = 0.f, b = 0.f, c = -1e30f, wv = 0.f;
        if (o < len) {
            float2 p = pts[start + o];
            a = TWO_EXPC * p.x;
            b = TWO_EXPC * p.y;
            c = -EXPC * fmaf(p.x, p.x, p.y * p.y);
            if (W) wv = wgt[start + o];
        }
        int g4 = 4 * (tid >> 1) + (tid & 1);
        sAB[g4] = a;  sAB[g4 + 2] = b;
        sCW[g4] = c;  sCW[g4 + 2] = wv;
        __syncthreads();

        int cnt = min(TILE, len - r * TILE);
        int ng  = (cnt + 1) >> 1;
        const float4* AB4 = (const float4*)sAB;
        const float4* CW4 = (const float4*)sCW;
        for (int g = 0; g < ng; ++g) {
            float4 AB = AB4[g];
            float4 CW = CW4[g];
            v2f a01; a01.x = AB.x; a01.y = AB.y;
            v2f b01; b01.x = AB.z; b01.y = AB.w;
            v2f c01; c01.x = CW.x; c01.y = CW.y;
            v2f w01; w01.x = CW.z; w01.y = CW.w;
#pragma unroll
            for (int k = 0; k < MQ; ++k) {
                v2f t0, t1, e;
                asm("v_pk_add_f32 %0, %1, %2"
                    : "=v"(t0) : "v"(c01), "v"(qe2[k]));
                asm("v_pk_fma_f32 %0, %1, %2, %3"
                    : "=v"(t1) : "v"(b01), "v"(qy2[k]), "v"(t0));
                asm("v_pk_fma_f32 %0, %1, %2, %3"
                    : "=v"(e) : "v"(a01), "v"(qx2[k]), "v"(t1));
                float k0 = fast_exp2(e.x);
                float k1 = fast_exp2(e.y);
                if (W) {
                    acc[k].x = fmaf(w01.x, k0, acc[k].x);
                    acc[k].y = fmaf(w01.y, k1, acc[k].y);
                } else {
                    acc[k].x += k0;
                    acc[k].y += k1;
                }
            }
        }
    }
}

__global__ __launch_bounds__(256) void kdeA(
    const float2* __restrict__ mc2,
    const float2* __restrict__ tr2,
    const float2* __restrict__ te2,
    const float2* __restrict__ bx2,
    const float*  __restrict__ ws,
    float* __restrict__ P)
{
    __shared__ float sAB[2 * TILE];
    __shared__ float sCW[2 * TILE];

    int tid   = threadIdx.x;
    int bin   = blockIdx.y;
    int slice = blockIdx.z;
    int base  = blockIdx.x * (256 * MQ);

    int qi[MQ];
    float qx[MQ], qy[MQ], qe[MQ];
#pragma unroll
    for (int k = 0; k < MQ; ++k) {
        qi[k] = base + k * 256 + tid;
        int qs = qi[k] < NMC ? qi[k] : (NMC - 1);
        float2 q = mc2[bin * NMC + qs];
        qx[k] = q.x;
        qy[k] = q.y;
        qe[k] = -EXPC * fmaf(q.x, q.x, q.y * q.y);
    }

    v2f acc[MQ];

    // phase 1: train
    phase<false>(tr2, nullptr, NTR, slice, sAB, sCW, qx, qy, qe, acc, tid);
#pragma unroll
    for (int k = 0; k < MQ; ++k)
        if (qi[k] < NMC)
            atomicAdd(&P[bin * NMC + qi[k]], acc[k].x + acc[k].y);

    // phase 2: test
    phase<false>(te2, nullptr, NTE, slice, sAB, sCW, qx, qy, qe, acc, tid);
#pragma unroll
    for (int k = 0; k < MQ; ++k)
        if (qi[k] < NMC)
            atomicAdd(&P[PLANE + bin * NMC + qi[k]], acc[k].x + acc[k].y);

    // phase 3: weighted batch
    phase<true>(bx2, ws + CW_OFF, BSZ, slice, sAB, sCW, qx, qy, qe, acc, tid);
#pragma unroll
    for (int k = 0; k < MQ; ++k)
        if (qi[k] < NMC)
            atomicAdd(&P[2 * PLANE + bin * NMC + qi[k]], acc[k].x + acc[k].y);
}

// ------------------------------------------------------------- combine ----
// P holds the full kernel sums (qe inside the exponent) — no rescaling here.
__global__ void combine_k(const float2* __restrict__ mc2,
                          const float*  __restrict__ Wm,
                          const float*  __restrict__ bv,
                          const float*  __restrict__ ws,
                          const float*  __restrict__ P,
                          float* __restrict__ S1, float* __restrict__ S2)
{
    int bin  = blockIdx.y;
    int m    = blockIdx.x * 256 + threadIdx.x;
    int lane = threadIdx.x & 63;

    float c1 = 0.f, c2 = 0.f;
    if (m < NMC) {
        float2 q = mc2[bin * NMC + m];
        int idx  = bin * NMC + m;
        float t_tr = P[idx];
        float t_te = P[PLANE + idx];
        float t_w  = P[2 * PLANE + idx];

        float lmax = -1e30f;
        float l[NCLS];
#pragma unroll
        for (int c = 0; c < NCLS; ++c) {
            l[c] = fmaf(q.x, Wm[c], fmaf(q.y, Wm[NCLS + c], bv[c]));
            lmax = fmaxf(lmax, l[c]);
        }
        float sume = 0.f;
#pragma unroll
        for (int c = 0; c < NCLS; ++c) sume += expf(l[c] - lmax);
        float hat_s = 1.0f / sume;

        const float step = 1.0f / 15.0f;
        float lo = bin * step;
        float hi = (bin == NB - 1) ? 1.0f : (bin + 1) * step;
        float ind = (hat_s >= lo && hat_s <= hi) ? 1.f : 0.f;

        float cnt    = ws[0];
        float kde_tr = t_tr * (1.0f / (NTR * KDE_NORM));
        float kde_te = t_te * (1.0f / (NTE * KDE_NORM));
        float kw     = t_w / (fmaxf(cnt, 1.0f) * KDE_NORM);
        float p_y    = cnt * (1.0f / BSZ);
        float p_hs   = kw * p_y / (kde_tr + 1e-8f);
        p_hs = fminf(fmaxf(p_hs, 0.f), 1.f);

        c1 = p_hs * ind * kde_te;
        c2 = p_hs * ind * kde_tr;
    }

    for (int off = 32; off > 0; off >>= 1) {
        c1 += __shfl_down(c1, off);
        c2 += __shfl_down(c2, off);
    }
    if (lane == 0) {
        atomicAdd(&S1[bin], c1);
        atomicAdd(&S2[bin], c2);
    }
}

// ------------------------------------- fallback (small ws): R2 kernel ----
template <int ROUNDS, bool WEIGHTED>
__device__ __forceinline__ float kde_phase_fb(const float2* __restrict__ pts,
                                              int Nq, float4* tile,
                                              const float* __restrict__ w,
                                              int tid, int wid,
                                              float qx, float qy, float qe)
{
    float acc = 0.f;
    for (int r = 0; r < ROUNDS; ++r) {
        __syncthreads();
        int off = r * TILE + tid;
#pragma unroll
        for (int s = 0; s < 4; ++s) {
            float4 v;
            if (off < Nq) {
                float2 p = pts[s * Nq + off];
                v.x = TWO_EXPC * p.x;
                v.y = TWO_EXPC * p.y;
                v.z = -EXPC * fmaf(p.x, p.x, p.y * p.y);
                v.w = WEIGHTED ? w[s * Nq + off] : 0.f;
            } else {
                v = make_float4(0.f, 0.f, -1e30f, 0.f);
            }
            tile[s * TILE + tid] = v;
        }
        __syncthreads();
        const float4* t4 = &tile[wid * TILE];
#pragma unroll 8
        for (int j = 0; j < TILE; ++j) {
            float4 v = t4[j];
            float e = fmaf(qx, v.x, fmaf(qy, v.y, v.z)) + qe;
            float k = fast_exp2(e);
            acc = WEIGHTED ? fmaf(v.w, k, acc) : (acc + k);
        }
    }
    return acc;
}

__global__ __launch_bounds__(256) void ec_kde_fb(
    const float2* __restrict__ mc2, const float2* __restrict__ train2,
    const float2* __restrict__ test2, const float2* __restrict__ batch2,
    const float* __restrict__ Wm, const float* __restrict__ bv,
    const float* __restrict__ ws, float* __restrict__ S1, float* __restrict__ S2)
{
    __shared__ float4 tile[4 * TILE];
    __shared__ float  red[3][256];

    int tid  = threadIdx.x;
    int wid  = tid >> 6;
    int lane = tid & 63;
    int bin  = blockIdx.y;
    int m    = blockIdx.x * 64 + lane;
    int mm   = (m < NMC) ? m : (NMC - 1);

    float2 q = mc2[bin * NMC + mm];
    float qx = q.x, qy = q.y;
    float qe = -EXPC * fmaf(qx, qx, qy * qy);

    float s_tr = kde_phase_fb<20, false>(train2, NTR / 4, tile, nullptr, tid, wid, qx, qy, qe);
    float s_te = kde_phase_fb<10, false>(test2,  NTE / 4, tile, nullptr, tid, wid, qx, qy, qe);
    float s_w  = kde_phase_fb<1,  true >(batch2, BSZ / 4, tile, ws + CW_OFF, tid, wid, qx, qy, qe);

    red[0][tid] = s_tr; red[1][tid] = s_te; red[2][tid] = s_w;
    __syncthreads();

    if (tid < 64) {
        float t_tr = ((red[0][tid] + red[0][tid + 64]) + (red[0][tid + 128] + red[0][tid + 192]));
        float t_te = ((red[1][tid] + red[1][tid + 64]) + (red[1][tid + 128] + red[1][tid + 192]));
        float t_w  = ((red[2][tid] + red[2][tid + 64]) + (red[2][tid + 128] + red[2][tid + 192]));

        float lmax = -1e30f;
        float l[NCLS];
#pragma unroll
        for (int c = 0; c < NCLS; ++c) {
            l[c] = fmaf(qx, Wm[c], fmaf(qy, Wm[NCLS + c], bv[c]));
            lmax = fmaxf(lmax, l[c]);
        }
        float sume = 0.f;
#pragma unroll
        for (int c = 0; c < NCLS; ++c) sume += expf(l[c] - lmax);
        float hat_s = 1.0f / sume;

        const float step = 1.0f / 15.0f;
        float lo = bin * step;
        float hi = (bin == NB - 1) ? 1.0f : (bin + 1) * step;
        float ind = (hat_s >= lo && hat_s <= hi) ? 1.f : 0.f;

        float cnt    = ws[0];
        float kde_tr = t_tr * (1.0f / (NTR * KDE_NORM));
        float kde_te = t_te * (1.0f / (NTE * KDE_NORM));
        float kw     = t_w / (fmaxf(cnt, 1.0f) * KDE_NORM);
        float p_y    = cnt * (1.0f / BSZ);
        float p_hs   = kw * p_y / (kde_tr + 1e-8f);
        p_hs = fminf(fmaxf(p_hs, 0.f), 1.f);

        bool valid = (m < NMC);
        float c1 = valid ? p_hs * ind * kde_te : 0.f;
        float c2 = valid ? p_hs * ind * kde_tr : 0.f;

        for (int off = 32; off > 0; off >>= 1) {
            c1 += __shfl_down(c1, off);
            c2 += __shfl_down(c2, off);
        }
        if (lane == 0) {
            atomicAdd(&S1[bin], c1);
            atomicAdd(&S2[bin], c2);
        }
    }
}

// ---------------------------------------------------------------- final ----
__global__ void final_k(const float* __restrict__ ws, float* __restrict__ out)
{
    if (threadIdx.x == 0 && blockIdx.x == 0) {
        float ec = 0.f;
        for (int b = 0; b < NB; ++b) {
            float tr_rate = ws[1  + b] * (1.0f / NTR);
            float te_rate = ws[16 + b] * (1.0f / NTE);
            float s1 = ws[32 + b];
            float s2 = ws[48 + b];
            float a_te = (te_rate > 0.f) ? (1.0f / te_rate) : 0.f;
            float a_tr = (tr_rate > 0.f) ? (1.0f / tr_rate) : 0.f;
            float integral = (a_te * s1 - a_tr * s2) * (1.0f / NMC) * 100.0f;
            if (te_rate > 0.f) ec += te_rate * fabsf(integral);
        }
        out[0] = ec;
    }
}

// --------------------------------------------------------------- launch ----
extern "C" void kernel_launch(void* const* d_in, const int* in_sizes, int n_in,
                              void* d_out, int out_size, void* d_ws, size_t ws_size,
                              hipStream_t stream)
{
    const float* batch_x = (const float*)d_in[0];
    const int*   by      = (const int*)  d_in[1];
    const int*   bp      = (const int*)  d_in[2];
    const float* trp     = (const float*)d_in[3];
    const float* tep     = (const float*)d_in[4];
    const float* train_x = (const float*)d_in[5];
    const float* test_x  = (const float*)d_in[6];
    const float* Wm      = (const float*)d_in[7];
    const float* bv      = (const float*)d_in[8];
    const float* mc      = (const float*)d_in[9];

    float* ws  = (float*)d_ws;
    float* out = (float*)d_out;

    bool big = ws_size >= (size_t)WS_BIG * sizeof(float);
    size_t zbytes = (big ? WS_BIG : WS_SMALL) * sizeof(float);
    hipMemsetAsync(d_ws, 0, zbytes, stream);

    int nthr = 256;
    int nblk = (NTR + nthr - 1) / nthr;
    setup_k<<<nblk, nthr, 0, stream>>>(by, bp, trp, tep, ws);

    if (big) {
        dim3 gA((NMC + 256 * MQ - 1) / (256 * MQ), NB, DS);
        kdeA<<<gA, 256, 0, stream>>>(
            (const float2*)mc, (const float2*)train_x, (const float2*)test_x,
            (const float2*)batch_x, ws, ws + P_OFF);

        dim3 gB((NMC + 255) / 256, NB);
        combine_k<<<gB, 256, 0, stream>>>(
            (const float2*)mc, Wm, bv, ws, ws + P_OFF, ws + 32, ws + 48);
    } else {
        dim3 grid((NMC + 63) / 64, NB);
        ec_kde_fb<<<grid, 256, 0, stream>>>(
            (const float2*)mc,
            (const float2*)train_x, (const float2*)test_x, (const float2*)batch_x,
            Wm, bv, ws, ws + 32, ws + 48);
    }

    final_k<<<1, 64, 0, stream>>>(ws, out);
}